// Round 1
// baseline (4883.043 us; speedup 1.0000x reference)
//
#include <hip/hip_runtime.h>

#define BN_EPS 1e-3f

// ---------------- small utility kernels ----------------

__global__ __launch_bounds__(256) void zero_kernel(float* p, int n) {
    int i = blockIdx.x * 256 + threadIdx.x;
    if (i < n) p[i] = 0.f;
}

__global__ __launch_bounds__(256) void copy_kernel(const float* __restrict__ in,
                                                   float* __restrict__ out, int n) {
    int i = blockIdx.x * 256 + threadIdx.x;
    if (i < n) out[i] = in[i];
}

// coords rows are (b, z, y, x); xyz = (x,y,z) * (voxel*stride) + (0,-40,-3)
__global__ __launch_bounds__(256) void xyz_kernel(const int* __restrict__ coords,
                                                  float* __restrict__ out, int N,
                                                  float sx, float sy, float sz) {
    int n = blockIdx.x * 256 + threadIdx.x;
    if (n >= N) return;
    int4 c = ((const int4*)coords)[n];  // x=b, y=z, z=y, w=x
    out[n * 3 + 0] = c.w * sx;
    out[n * 3 + 1] = c.z * sy - 40.0f;
    out[n * 3 + 2] = c.y * sz - 3.0f;
}

// ---------------- sparse conv (gather + per-thread dot) ----------------
// rb is [K, N] (row stride N), value = input row index or -1.
template <int CIN, int COUT>
__global__ __launch_bounds__(256) void sconv_kernel(const float* __restrict__ feat,
                                                    const int* __restrict__ rb,
                                                    const float* __restrict__ W,
                                                    float* __restrict__ out, int N, int K) {
    constexpr int ROWS = 256 / COUT;
    const int co = threadIdx.x % COUT;
    const int r = threadIdx.x / COUT;
    const long n = (long)blockIdx.x * ROWS + r;
    if (n >= N) return;
    float acc = 0.f;
    for (int k = 0; k < K; ++k) {
        int idx = rb[(size_t)k * N + n];
        if (idx >= 0) {
            const float* f = feat + (size_t)idx * CIN;
            const float* w = W + (size_t)k * CIN * COUT + co;
#pragma unroll
            for (int ci = 0; ci < CIN; ++ci) acc += f[ci] * w[(size_t)ci * COUT];
        }
    }
    out[n * COUT + co] = acc;
}

// ---------------- BN stats: per-channel sum & sumsq (stats pre-zeroed) ----------------
template <int C>
__global__ __launch_bounds__(256) void bn_stats_kernel(const float* __restrict__ x,
                                                       float* __restrict__ stats, int N) {
    constexpr int ROWS = 256 / C;
    const int c = threadIdx.x % C;
    const int r = threadIdx.x / C;
    float s = 0.f, ss = 0.f;
    for (long n = (long)blockIdx.x * ROWS + r; n < N; n += (long)gridDim.x * ROWS) {
        float v = x[n * C + c];
        s += v;
        ss += v * v;
    }
    __shared__ float sh0[256];
    __shared__ float sh1[256];
    sh0[threadIdx.x] = s;
    sh1[threadIdx.x] = ss;
    __syncthreads();
    for (int st = ROWS / 2; st > 0; st >>= 1) {
        if (r < st) {
            sh0[threadIdx.x] += sh0[threadIdx.x + st * C];
            sh1[threadIdx.x] += sh1[threadIdx.x + st * C];
        }
        __syncthreads();
    }
    if (r == 0) {
        atomicAdd(&stats[c], sh0[c]);
        atomicAdd(&stats[C + c], sh1[c]);
    }
}

// ---------------- BN apply + ReLU (in place) ----------------
template <int C>
__global__ __launch_bounds__(256) void bn_apply_kernel(float* __restrict__ x,
                                                       const float* __restrict__ stats,
                                                       const float* __restrict__ g,
                                                       const float* __restrict__ b, int N) {
    long i = (long)blockIdx.x * 256 + threadIdx.x;
    long total = (long)N * C;
    if (i >= total) return;
    int c = (int)(i % C);
    float inv = 1.0f / (float)N;
    float m = stats[c] * inv;
    float v = stats[C + c] * inv - m * m;
    float sc = g[c] / sqrtf(v + BN_EPS);
    float y = (x[i] - m) * sc + b[c];
    x[i] = fmaxf(y, 0.f);
}

// ---------------- one layer = conv -> zero stats -> stats -> apply ----------------
template <int CIN, int COUT>
static void layer(const float* fin, const int* rb, int K, int N, const float* W, const float* g,
                  const float* b, float* fout, float* stats, hipStream_t stream) {
    int blocks = (int)(((long)N * COUT + 255) / 256);
    hipLaunchKernelGGL((sconv_kernel<CIN, COUT>), dim3(blocks), dim3(256), 0, stream, fin, rb, W,
                       fout, N, K);
    hipLaunchKernelGGL(zero_kernel, dim3(1), dim3(256), 0, stream, stats, 2 * COUT);
    constexpr int ROWS = 256 / COUT;
    int sb = (int)((N + ROWS - 1) / ROWS);
    if (sb > 1024) sb = 1024;
    if (sb < 1) sb = 1;
    hipLaunchKernelGGL((bn_stats_kernel<COUT>), dim3(sb), dim3(256), 0, stream, fout, stats, N);
    hipLaunchKernelGGL((bn_apply_kernel<COUT>), dim3(blocks), dim3(256), 0, stream, fout, stats, g,
                       b, N);
}

extern "C" void kernel_launch(void* const* d_in, const int* in_sizes, int n_in, void* d_out,
                              int out_size, void* d_ws, size_t ws_size, hipStream_t stream) {
    const float* features = (const float*)d_in[0];
    const float* W[14];
    const float* G[14];
    const float* Bb[14];
    for (int i = 0; i < 14; ++i) {
        W[i] = (const float*)d_in[1 + 3 * i];
        G[i] = (const float*)d_in[2 + 3 * i];
        Bb[i] = (const float*)d_in[3 + 3 * i];
    }
    const int* coords0 = (const int*)d_in[43];
    const int* coords1 = (const int*)d_in[44];
    const int* coords2 = (const int*)d_in[45];
    const int* coords3 = (const int*)d_in[46];
    const int* rb0 = (const int*)d_in[47];
    const int* rbc1 = (const int*)d_in[48];
    const int* rb1 = (const int*)d_in[49];
    const int* rbc2 = (const int*)d_in[50];
    const int* rb2 = (const int*)d_in[51];
    const int* rbc3 = (const int*)d_in[52];
    const int* rb3 = (const int*)d_in[53];
    const int* rbc4 = (const int*)d_in[54];

    const int N0 = in_sizes[0] / 4;
    const int N1 = in_sizes[44] / 4;
    const int N2 = in_sizes[45] / 4;
    const int N3 = in_sizes[46] / 4;
    const int N4 = in_sizes[54] / 3;

    float* out = (float*)d_out;
    long off = 0;
    float* xyz0 = out + off; off += (long)N0 * 3;
    float* f0   = out + off; off += (long)N0 * 4;
    float* xyz1 = out + off; off += (long)N1 * 3;
    float* f1   = out + off; off += (long)N1 * 32;
    float* xyz2 = out + off; off += (long)N2 * 3;
    float* f2   = out + off; off += (long)N2 * 64;
    float* xyz3 = out + off; off += (long)N3 * 3;
    float* f3   = out + off; off += (long)N3 * 64;
    float* f4   = out + off;

    long maxN = N0;
    if (N1 > maxN) maxN = N1;
    if (N2 > maxN) maxN = N2;
    if (N3 > maxN) maxN = N3;
    if (N4 > maxN) maxN = N4;

    float* bufA = (float*)d_ws;
    float* bufB = bufA + (size_t)maxN * 64;
    float* stats = bufB + (size_t)maxN * 64;

    // outputs that don't depend on the conv stack
    hipLaunchKernelGGL(copy_kernel, dim3((N0 * 4 + 255) / 256), dim3(256), 0, stream, features, f0,
                       N0 * 4);
    hipLaunchKernelGGL(xyz_kernel, dim3((N0 + 255) / 256), dim3(256), 0, stream, coords0, xyz0, N0,
                       0.05f, 0.05f, 0.1f);
    hipLaunchKernelGGL(xyz_kernel, dim3((N1 + 255) / 256), dim3(256), 0, stream, coords1, xyz1, N1,
                       0.1f, 0.1f, 0.2f);
    hipLaunchKernelGGL(xyz_kernel, dim3((N2 + 255) / 256), dim3(256), 0, stream, coords2, xyz2, N2,
                       0.2f, 0.2f, 0.4f);
    hipLaunchKernelGGL(xyz_kernel, dim3((N3 + 255) / 256), dim3(256), 0, stream, coords3, xyz3, N3,
                       0.4f, 0.4f, 0.8f);

    // conv stack
    layer<4, 16>(features, rb0, 27, N0, W[0], G[0], Bb[0], bufA, stats, stream);
    layer<16, 16>(bufA, rb0, 27, N0, W[1], G[1], Bb[1], bufB, stats, stream);
    layer<16, 32>(bufB, rbc1, 27, N1, W[2], G[2], Bb[2], f1, stats, stream);
    layer<32, 32>(f1, rb1, 27, N1, W[3], G[3], Bb[3], bufA, stats, stream);
    layer<32, 32>(bufA, rb1, 27, N1, W[4], G[4], Bb[4], bufB, stats, stream);
    layer<32, 64>(bufB, rbc2, 27, N2, W[5], G[5], Bb[5], f2, stats, stream);
    layer<64, 64>(f2, rb2, 27, N2, W[6], G[6], Bb[6], bufA, stats, stream);
    layer<64, 64>(bufA, rb2, 27, N2, W[7], G[7], Bb[7], bufB, stats, stream);
    layer<64, 64>(bufB, rb2, 27, N2, W[8], G[8], Bb[8], bufA, stats, stream);
    layer<64, 64>(bufA, rbc3, 27, N3, W[9], G[9], Bb[9], f3, stats, stream);
    layer<64, 64>(f3, rb3, 27, N3, W[10], G[10], Bb[10], bufA, stats, stream);
    layer<64, 64>(bufA, rb3, 27, N3, W[11], G[11], Bb[11], bufB, stats, stream);
    layer<64, 64>(bufB, rb3, 27, N3, W[12], G[12], Bb[12], bufA, stats, stream);
    layer<64, 64>(bufA, rbc4, 3, N4, W[13], G[13], Bb[13], f4, stats, stream);
}

// Round 2
// 3675.519 us; speedup vs baseline: 1.3285x; 1.3285x over previous
//
#include <hip/hip_runtime.h>

#define BN_EPS 1e-3f

// ---------------- small utility kernels ----------------

__global__ __launch_bounds__(256) void zero_kernel(float* p, int n) {
    int i = blockIdx.x * 256 + threadIdx.x;
    if (i < n) p[i] = 0.f;
}

__global__ __launch_bounds__(256) void copy_kernel(const float* __restrict__ in,
                                                   float* __restrict__ out, int n) {
    int i = blockIdx.x * 256 + threadIdx.x;
    if (i < n) out[i] = in[i];
}

// coords rows are (b, z, y, x); xyz = (x,y,z) * (voxel*stride) + (0,-40,-3)
__global__ __launch_bounds__(256) void xyz_kernel(const int* __restrict__ coords,
                                                  float* __restrict__ out, int N,
                                                  float sx, float sy, float sz) {
    int n = blockIdx.x * 256 + threadIdx.x;
    if (n >= N) return;
    int4 c = ((const int4*)coords)[n];  // x=b, y=z, z=y, w=x
    out[n * 3 + 0] = c.w * sx;
    out[n * 3 + 1] = c.z * sy - 40.0f;
    out[n * 3 + 2] = c.y * sz - 3.0f;
}

// ---------------- tiled sparse conv + fused BN-stats ----------------
// rb is [K, N]; out tile = 64 rows x COUT. Per k: gather feat rows -> LDS,
// stage W[k] -> LDS (both register-prefetched for k+1), register-tiled FMA.
// Epilogue: per-channel sum/sumsq block-reduced, atomicAdd into stats[2*COUT].
template <int CIN, int COUT>
__global__ __launch_bounds__(256) void sconv_tiled(const float* __restrict__ feat,
                                                   const int* __restrict__ rb,
                                                   const float* __restrict__ W,
                                                   float* __restrict__ out,
                                                   float* __restrict__ stats, int N, int K) {
    constexpr int MT = 64;           // rows per block
    constexpr int FP = CIN + 4;      // padded feat row stride (multiple of 4 -> b128 aligned)
    constexpr int CT = COUT / 16;    // channels per thread
    constexpr int FN = MT * CIN / 4; // float4 elements to stage for feat
    constexpr int WN = CIN * COUT / 4;
    constexpr int FPT = (FN + 255) / 256;
    constexpr int WPT = (WN + 255) / 256;
    constexpr int SEGS = CIN / 4;

    __shared__ float sF[MT * FP];
    __shared__ float sW[CIN * COUT];

    const int tid = threadIdx.x;
    const long n0 = (long)blockIdx.x * MT;
    const int cg = tid % 16;  // col group
    const int rg = tid / 16;  // row group (16 groups of 4 rows)

    float4 pf[FPT];
    float4 pw[WPT];

    auto prefetch = [&](int k) {
#pragma unroll
        for (int j = 0; j < FPT; ++j) {
            int e = tid + j * 256;
            if (e < FN) {
                int row = e / SEGS, seg = e % SEGS;
                long nrow = n0 + row;
                int idx = (nrow < N) ? rb[(size_t)k * N + nrow] : -1;
                pf[j] = (idx >= 0) ? *(const float4*)(feat + (size_t)idx * CIN + seg * 4)
                                   : float4{0.f, 0.f, 0.f, 0.f};
            }
        }
#pragma unroll
        for (int j = 0; j < WPT; ++j) {
            int e = tid + j * 256;
            if (e < WN) pw[j] = *(const float4*)(W + (size_t)k * CIN * COUT + e * 4);
        }
    };
    auto stage = [&]() {
#pragma unroll
        for (int j = 0; j < FPT; ++j) {
            int e = tid + j * 256;
            if (e < FN) {
                int row = e / SEGS, seg = e % SEGS;
                *(float4*)&sF[row * FP + seg * 4] = pf[j];
            }
        }
#pragma unroll
        for (int j = 0; j < WPT; ++j) {
            int e = tid + j * 256;
            if (e < WN) *(float4*)&sW[e * 4] = pw[j];
        }
    };

    float acc[4][CT];
#pragma unroll
    for (int rr = 0; rr < 4; ++rr)
#pragma unroll
        for (int cc = 0; cc < CT; ++cc) acc[rr][cc] = 0.f;

    prefetch(0);
    for (int k = 0; k < K; ++k) {
        __syncthreads();  // previous compute done before LDS overwrite
        stage();
        __syncthreads();
        if (k + 1 < K) prefetch(k + 1);
        // compute tile from LDS
#pragma unroll
        for (int ci = 0; ci < CIN; ci += 4) {
            float4 f[4];
#pragma unroll
            for (int rr = 0; rr < 4; ++rr)
                f[rr] = *(const float4*)&sF[(rg * 4 + rr) * FP + ci];
#pragma unroll
            for (int j = 0; j < 4; ++j) {
                float wv[CT];
                if constexpr (CT == 4) {
                    float4 t = *(const float4*)&sW[(ci + j) * COUT + cg * 4];
                    wv[0] = t.x; wv[1] = t.y; wv[2] = t.z; wv[3] = t.w;
                } else if constexpr (CT == 2) {
                    float2 t = *(const float2*)&sW[(ci + j) * COUT + cg * 2];
                    wv[0] = t.x; wv[1] = t.y;
                } else {
                    wv[0] = sW[(ci + j) * COUT + cg];
                }
                const float* fp0 = (const float*)&f[0];
                const float* fp1 = (const float*)&f[1];
                const float* fp2 = (const float*)&f[2];
                const float* fp3 = (const float*)&f[3];
#pragma unroll
                for (int cc = 0; cc < CT; ++cc) {
                    acc[0][cc] += fp0[j] * wv[cc];
                    acc[1][cc] += fp1[j] * wv[cc];
                    acc[2][cc] += fp2[j] * wv[cc];
                    acc[3][cc] += fp3[j] * wv[cc];
                }
            }
        }
    }

    // store outputs
#pragma unroll
    for (int rr = 0; rr < 4; ++rr) {
        long nrow = n0 + rg * 4 + rr;
        if (nrow < N) {
            float* o = out + nrow * COUT + cg * CT;
            if constexpr (CT == 4) {
                *(float4*)o = float4{acc[rr][0], acc[rr][1], acc[rr][2], acc[rr][3]};
            } else if constexpr (CT == 2) {
                *(float2*)o = float2{acc[rr][0], acc[rr][1]};
            } else {
                o[0] = acc[rr][0];
            }
        }
    }

    // fused BN stats: rows >= N contributed exact zeros (gather zero-fills), safe to sum.
    float s[CT], ss[CT];
#pragma unroll
    for (int cc = 0; cc < CT; ++cc) {
        s[cc] = acc[0][cc] + acc[1][cc] + acc[2][cc] + acc[3][cc];
        ss[cc] = acc[0][cc] * acc[0][cc] + acc[1][cc] * acc[1][cc] +
                 acc[2][cc] * acc[2][cc] + acc[3][cc] * acc[3][cc];
    }
    __syncthreads();  // all compute reads of sF done; reuse as scratch
    float* rs = sF;               // [16][COUT]
    float* rss = sF + 16 * COUT;  // [16][COUT]
#pragma unroll
    for (int cc = 0; cc < CT; ++cc) {
        rs[rg * COUT + cg * CT + cc] = s[cc];
        rss[rg * COUT + cg * CT + cc] = ss[cc];
    }
    __syncthreads();
    for (int st = 8; st >= 1; st >>= 1) {
        if (rg < st) {
#pragma unroll
            for (int cc = 0; cc < CT; ++cc) {
                int c = cg * CT + cc;
                rs[rg * COUT + c] += rs[(rg + st) * COUT + c];
                rss[rg * COUT + c] += rss[(rg + st) * COUT + c];
            }
        }
        __syncthreads();
    }
    if (rg == 0) {
#pragma unroll
        for (int cc = 0; cc < CT; ++cc) {
            int c = cg * CT + cc;
            atomicAdd(&stats[c], rs[c]);
            atomicAdd(&stats[COUT + c], rss[c]);
        }
    }
}

// ---------------- BN apply + ReLU (in place) ----------------
template <int C>
__global__ __launch_bounds__(256) void bn_apply_kernel(float* __restrict__ x,
                                                       const float* __restrict__ stats,
                                                       const float* __restrict__ g,
                                                       const float* __restrict__ b, int N) {
    long i = (long)blockIdx.x * 256 + threadIdx.x;
    long total = (long)N * C;
    if (i >= total) return;
    int c = (int)(i % C);
    float inv = 1.0f / (float)N;
    float m = stats[c] * inv;
    float v = stats[C + c] * inv - m * m;
    float sc = g[c] / sqrtf(v + BN_EPS);
    float y = (x[i] - m) * sc + b[c];
    x[i] = fmaxf(y, 0.f);
}

// ---------------- one layer = conv(+stats) -> apply ----------------
template <int CIN, int COUT>
static void layer(const float* fin, const int* rb, int K, int N, const float* W, const float* g,
                  const float* b, float* fout, float* stats, hipStream_t stream) {
    int cblocks = (int)((N + 63) / 64);
    hipLaunchKernelGGL((sconv_tiled<CIN, COUT>), dim3(cblocks), dim3(256), 0, stream, fin, rb, W,
                       fout, stats, N, K);
    int ablocks = (int)(((long)N * COUT + 255) / 256);
    hipLaunchKernelGGL((bn_apply_kernel<COUT>), dim3(ablocks), dim3(256), 0, stream, fout, stats, g,
                       b, N);
}

extern "C" void kernel_launch(void* const* d_in, const int* in_sizes, int n_in, void* d_out,
                              int out_size, void* d_ws, size_t ws_size, hipStream_t stream) {
    const float* features = (const float*)d_in[0];
    const float* W[14];
    const float* G[14];
    const float* Bb[14];
    for (int i = 0; i < 14; ++i) {
        W[i] = (const float*)d_in[1 + 3 * i];
        G[i] = (const float*)d_in[2 + 3 * i];
        Bb[i] = (const float*)d_in[3 + 3 * i];
    }
    const int* coords0 = (const int*)d_in[43];
    const int* coords1 = (const int*)d_in[44];
    const int* coords2 = (const int*)d_in[45];
    const int* coords3 = (const int*)d_in[46];
    const int* rb0 = (const int*)d_in[47];
    const int* rbc1 = (const int*)d_in[48];
    const int* rb1 = (const int*)d_in[49];
    const int* rbc2 = (const int*)d_in[50];
    const int* rb2 = (const int*)d_in[51];
    const int* rbc3 = (const int*)d_in[52];
    const int* rb3 = (const int*)d_in[53];
    const int* rbc4 = (const int*)d_in[54];

    const int N0 = in_sizes[0] / 4;
    const int N1 = in_sizes[44] / 4;
    const int N2 = in_sizes[45] / 4;
    const int N3 = in_sizes[46] / 4;
    const int N4 = in_sizes[54] / 3;

    float* out = (float*)d_out;
    long off = 0;
    float* xyz0 = out + off; off += (long)N0 * 3;
    float* f0   = out + off; off += (long)N0 * 4;
    float* xyz1 = out + off; off += (long)N1 * 3;
    float* f1   = out + off; off += (long)N1 * 32;
    float* xyz2 = out + off; off += (long)N2 * 3;
    float* f2   = out + off; off += (long)N2 * 64;
    float* xyz3 = out + off; off += (long)N3 * 3;
    float* f3   = out + off; off += (long)N3 * 64;
    float* f4   = out + off;

    long maxN = N0;
    if (N1 > maxN) maxN = N1;
    if (N2 > maxN) maxN = N2;
    if (N3 > maxN) maxN = N3;
    if (N4 > maxN) maxN = N4;

    float* bufA = (float*)d_ws;
    float* bufB = bufA + (size_t)maxN * 64;
    float* statsBase = bufB + (size_t)maxN * 64;  // 14 slots x 128 floats

    // zero all BN stat slots once
    hipLaunchKernelGGL(zero_kernel, dim3((14 * 128 + 255) / 256), dim3(256), 0, stream, statsBase,
                       14 * 128);

    // outputs that don't depend on the conv stack
    hipLaunchKernelGGL(copy_kernel, dim3((N0 * 4 + 255) / 256), dim3(256), 0, stream, features, f0,
                       N0 * 4);
    hipLaunchKernelGGL(xyz_kernel, dim3((N0 + 255) / 256), dim3(256), 0, stream, coords0, xyz0, N0,
                       0.05f, 0.05f, 0.1f);
    hipLaunchKernelGGL(xyz_kernel, dim3((N1 + 255) / 256), dim3(256), 0, stream, coords1, xyz1, N1,
                       0.1f, 0.1f, 0.2f);
    hipLaunchKernelGGL(xyz_kernel, dim3((N2 + 255) / 256), dim3(256), 0, stream, coords2, xyz2, N2,
                       0.2f, 0.2f, 0.4f);
    hipLaunchKernelGGL(xyz_kernel, dim3((N3 + 255) / 256), dim3(256), 0, stream, coords3, xyz3, N3,
                       0.4f, 0.4f, 0.8f);

    float* st = statsBase;
    // conv stack
    layer<4, 16>(features, rb0, 27, N0, W[0], G[0], Bb[0], bufA, st + 0 * 128, stream);
    layer<16, 16>(bufA, rb0, 27, N0, W[1], G[1], Bb[1], bufB, st + 1 * 128, stream);
    layer<16, 32>(bufB, rbc1, 27, N1, W[2], G[2], Bb[2], f1, st + 2 * 128, stream);
    layer<32, 32>(f1, rb1, 27, N1, W[3], G[3], Bb[3], bufA, st + 3 * 128, stream);
    layer<32, 32>(bufA, rb1, 27, N1, W[4], G[4], Bb[4], bufB, st + 4 * 128, stream);
    layer<32, 64>(bufB, rbc2, 27, N2, W[5], G[5], Bb[5], f2, st + 5 * 128, stream);
    layer<64, 64>(f2, rb2, 27, N2, W[6], G[6], Bb[6], bufA, st + 6 * 128, stream);
    layer<64, 64>(bufA, rb2, 27, N2, W[7], G[7], Bb[7], bufB, st + 7 * 128, stream);
    layer<64, 64>(bufB, rb2, 27, N2, W[8], G[8], Bb[8], bufA, st + 8 * 128, stream);
    layer<64, 64>(bufA, rbc3, 27, N3, W[9], G[9], Bb[9], f3, st + 9 * 128, stream);
    layer<64, 64>(f3, rb3, 27, N3, W[10], G[10], Bb[10], bufA, st + 10 * 128, stream);
    layer<64, 64>(bufA, rb3, 27, N3, W[11], G[11], Bb[11], bufB, st + 11 * 128, stream);
    layer<64, 64>(bufB, rb3, 27, N3, W[12], G[12], Bb[12], bufA, st + 12 * 128, stream);
    layer<64, 64>(bufA, rbc4, 3, N4, W[13], G[13], Bb[13], f4, st + 13 * 128, stream);
}

// Round 3
// 2390.816 us; speedup vs baseline: 2.0424x; 1.5373x over previous
//
#include <hip/hip_runtime.h>

#define BN_EPS 1e-3f

typedef __attribute__((ext_vector_type(8))) short short8;
typedef __attribute__((ext_vector_type(4))) float float4v;

__device__ __forceinline__ short f2bf(float f) {
    unsigned u = __float_as_uint(f);
    unsigned r = (u + 0x7FFFu + ((u >> 16) & 1u)) >> 16;
    return (short)r;
}

// ---------------- small utility kernels ----------------

__global__ __launch_bounds__(256) void zero_kernel(float* p, int n) {
    int i = blockIdx.x * 256 + threadIdx.x;
    if (i < n) p[i] = 0.f;
}

__global__ __launch_bounds__(256) void copy_kernel(const float* __restrict__ in,
                                                   float* __restrict__ out, int n) {
    int i = blockIdx.x * 256 + threadIdx.x;
    if (i < n) out[i] = in[i];
}

// coords rows are (b, z, y, x); xyz = (x,y,z) * (voxel*stride) + (0,-40,-3)
__global__ __launch_bounds__(256) void xyz_kernel(const int* __restrict__ coords,
                                                  float* __restrict__ out, int N,
                                                  float sx, float sy, float sz) {
    int n = blockIdx.x * 256 + threadIdx.x;
    if (n >= N) return;
    int4 c = ((const int4*)coords)[n];  // x=b, y=z, z=y, w=x
    out[n * 3 + 0] = c.w * sx;
    out[n * 3 + 1] = c.z * sy - 40.0f;
    out[n * 3 + 2] = c.y * sz - 3.0f;
}

// f0 (N x 4 fp32) -> bf16 padded (N x 32)
__global__ __launch_bounds__(256) void convert_f0(const float* __restrict__ f,
                                                  short* __restrict__ dst, int N) {
    int i = blockIdx.x * 256 + threadIdx.x;
    if (i >= N * 32) return;
    int c = i & 31, n = i >> 5;
    dst[i] = (c < 4) ? f2bf(f[n * 4 + c]) : (short)0;
}

// W [K][CIN][COUT] fp32 -> Wt [K][COUT][CHP] bf16 (ci zero-padded to CHP)
__global__ __launch_bounds__(256) void prep_w(const float* __restrict__ w,
                                              short* __restrict__ dst, int K, int CIN, int COUT,
                                              int CHP) {
    int i = blockIdx.x * 256 + threadIdx.x;
    int tot = K * COUT * CHP;
    if (i >= tot) return;
    int ci = i % CHP;
    int co = (i / CHP) % COUT;
    int k = i / (CHP * COUT);
    float v = (ci < CIN) ? w[((size_t)k * CIN + ci) * COUT + co] : 0.f;
    dst[i] = f2bf(v);
}

// ---------------- MFMA sparse conv, 1 wave/block, 16 rows x (CT*16) cols ----------------
// feat: bf16 [Nin][CH*32]; Wt: bf16 [K][COUT][CH*32]; rb: [K][N] (-1 = none)
// Fused BN stats: atomicAdd per-channel sum/sumsq into stats[2*COUT].
template <int CH, int CT, int COUT>
__global__ __launch_bounds__(64) void sconv_mfma(const short* __restrict__ feat,
                                                 const int* __restrict__ rb,
                                                 const short* __restrict__ Wt,
                                                 float* __restrict__ out,
                                                 float* __restrict__ stats, int N, int K) {
    constexpr int CHP = CH * 32;
    const int lane = threadIdx.x;
    const int quad = lane >> 4;
    const int l16 = lane & 15;
    const int m0 = blockIdx.x * 16;
    const int row = m0 + l16;
    const int rowc = (row < N - 1) ? row : (N - 1);
    const int colbase = blockIdx.y * (CT * 16);

    float4v acc[CT];
#pragma unroll
    for (int t = 0; t < CT; ++t) acc[t] = (float4v)0.f;

    struct Slot {
        short8 a[CH];
        short8 b[CH][CT];
    };

    auto load = [&](int k) {
        Slot s;
        int idx = rb[(size_t)k * N + rowc];
        bool valid = (row < N) && (idx >= 0);
        int cidx = idx >= 0 ? idx : 0;
        const short* fr = feat + (size_t)cidx * CHP + quad * 8;
        const short* wr = Wt + ((size_t)k * COUT + colbase + l16) * CHP + quad * 8;
#pragma unroll
        for (int c = 0; c < CH; ++c) {
            s.a[c] = *(const short8*)(fr + c * 32);
            s.a[c] = valid ? s.a[c] : (short8)0;
#pragma unroll
            for (int t = 0; t < CT; ++t)
                s.b[c][t] = *(const short8*)(wr + (size_t)t * 16 * CHP + c * 32);
        }
        return s;
    };

    Slot cur = load(0);
    Slot nxt = (K > 1) ? load(1) : cur;
    for (int k = 0; k < K; ++k) {
        Slot fut = (k + 2 < K) ? load(k + 2) : nxt;
#pragma unroll
        for (int c = 0; c < CH; ++c)
#pragma unroll
            for (int t = 0; t < CT; ++t)
                acc[t] = __builtin_amdgcn_mfma_f32_16x16x32_bf16(cur.a[c], cur.b[c][t], acc[t], 0,
                                                                 0, 0);
        cur = nxt;
        nxt = fut;
    }

    // D layout: col = lane&15 (within 16-col tile), row = quad*4 + reg
#pragma unroll
    for (int t = 0; t < CT; ++t) {
        int col = colbase + t * 16 + l16;
#pragma unroll
        for (int r = 0; r < 4; ++r) {
            int orow = m0 + quad * 4 + r;
            if (orow < N) out[(size_t)orow * COUT + col] = acc[t][r];
        }
        // fused BN stats (rows >= N contributed exact zeros)
        float s = acc[t][0] + acc[t][1] + acc[t][2] + acc[t][3];
        float ss = acc[t][0] * acc[t][0] + acc[t][1] * acc[t][1] + acc[t][2] * acc[t][2] +
                   acc[t][3] * acc[t][3];
        s += __shfl_xor(s, 16);
        s += __shfl_xor(s, 32);
        ss += __shfl_xor(ss, 16);
        ss += __shfl_xor(ss, 32);
        if (lane < 16) {
            atomicAdd(&stats[col], s);
            atomicAdd(&stats[COUT + col], ss);
        }
    }
}

// ---------------- BN apply + ReLU; writes bf16 (padded) for next layer, optional fp32 out ----
template <int COUT, int CHPN, bool F32OUT, bool BFOUT>
__global__ __launch_bounds__(256) void bn_apply(const float* __restrict__ x,
                                                const float* __restrict__ stats,
                                                const float* __restrict__ g,
                                                const float* __restrict__ b,
                                                float* __restrict__ fout,
                                                short* __restrict__ bfout, int N) {
    constexpr int CW = BFOUT ? CHPN : COUT;
    long i = (long)blockIdx.x * 256 + threadIdx.x;
    if (i >= (long)N * CW) return;
    int c = (int)(i % CW);
    long n = i / CW;
    float y = 0.f;
    if (c < COUT) {
        float inv = 1.0f / (float)N;
        float m = stats[c] * inv;
        float v = stats[COUT + c] * inv - m * m;
        float sc = g[c] / sqrtf(v + BN_EPS);
        y = fmaxf((x[n * COUT + c] - m) * sc + b[c], 0.f);
        if (F32OUT) fout[n * COUT + c] = y;
    }
    if (BFOUT) bfout[n * CHPN + c] = f2bf(y);
}

// ---------------- host side ----------------

template <int CH, int CT, int COUT>
static void conv(const short* fin, const int* rb, const short* wt, float* preact, float* stats,
                 int N, int K, hipStream_t stream) {
    dim3 grid((N + 15) / 16, COUT / (CT * 16));
    hipLaunchKernelGGL((sconv_mfma<CH, CT, COUT>), grid, dim3(64), 0, stream, fin, rb, wt, preact,
                       stats, N, K);
}

template <int COUT, int CHPN, bool F32OUT, bool BFOUT>
static void apply(const float* preact, const float* stats, const float* g, const float* b,
                  float* fout, short* bfout, int N, hipStream_t stream) {
    constexpr int CW = BFOUT ? CHPN : COUT;
    int blocks = (int)(((long)N * CW + 255) / 256);
    hipLaunchKernelGGL((bn_apply<COUT, CHPN, F32OUT, BFOUT>), dim3(blocks), dim3(256), 0, stream,
                       preact, stats, g, b, fout, bfout, N);
}

extern "C" void kernel_launch(void* const* d_in, const int* in_sizes, int n_in, void* d_out,
                              int out_size, void* d_ws, size_t ws_size, hipStream_t stream) {
    const float* features = (const float*)d_in[0];
    const float* W[14];
    const float* G[14];
    const float* Bb[14];
    for (int i = 0; i < 14; ++i) {
        W[i] = (const float*)d_in[1 + 3 * i];
        G[i] = (const float*)d_in[2 + 3 * i];
        Bb[i] = (const float*)d_in[3 + 3 * i];
    }
    const int* coords0 = (const int*)d_in[43];
    const int* coords1 = (const int*)d_in[44];
    const int* coords2 = (const int*)d_in[45];
    const int* coords3 = (const int*)d_in[46];
    const int* rb0 = (const int*)d_in[47];
    const int* rbc1 = (const int*)d_in[48];
    const int* rb1 = (const int*)d_in[49];
    const int* rbc2 = (const int*)d_in[50];
    const int* rb2 = (const int*)d_in[51];
    const int* rbc3 = (const int*)d_in[52];
    const int* rb3 = (const int*)d_in[53];
    const int* rbc4 = (const int*)d_in[54];

    const int N0 = in_sizes[0] / 4;
    const int N1 = in_sizes[44] / 4;
    const int N2 = in_sizes[45] / 4;
    const int N3 = in_sizes[46] / 4;
    const int N4 = in_sizes[54] / 3;

    float* out = (float*)d_out;
    long off = 0;
    float* xyz0 = out + off; off += (long)N0 * 3;
    float* f0   = out + off; off += (long)N0 * 4;
    float* xyz1 = out + off; off += (long)N1 * 3;
    float* f1   = out + off; off += (long)N1 * 32;
    float* xyz2 = out + off; off += (long)N2 * 3;
    float* f2   = out + off; off += (long)N2 * 64;
    float* xyz3 = out + off; off += (long)N3 * 3;
    float* f3   = out + off; off += (long)N3 * 64;
    float* f4   = out + off;

    long maxN = N0;
    if (N1 > maxN) maxN = N1;
    if (N2 > maxN) maxN = N2;
    if (N3 > maxN) maxN = N3;
    if (N4 > maxN) maxN = N4;

    // workspace layout
    float* preact = (float*)d_ws;                      // maxN*64 fp32
    float* statsBase = preact + (size_t)maxN * 64;     // 14*128 fp32
    short* bfA = (short*)(statsBase + 14 * 128);       // maxN*64 bf16
    short* bfB = bfA + (size_t)maxN * 64;              // maxN*64 bf16
    short* wtBase = bfB + (size_t)maxN * 64;           // transposed bf16 weights

    static const int KK[14] = {27, 27, 27, 27, 27, 27, 27, 27, 27, 27, 27, 27, 27, 3};
    static const int CI[14] = {4, 16, 16, 32, 32, 32, 64, 64, 64, 64, 64, 64, 64, 64};
    static const int CO[14] = {16, 16, 32, 32, 32, 64, 64, 64, 64, 64, 64, 64, 64, 64};
    short* WT[14];
    {
        size_t o = 0;
        for (int l = 0; l < 14; ++l) {
            WT[l] = wtBase + o;
            int chp = CI[l] <= 32 ? 32 : 64;
            o += (size_t)KK[l] * CO[l] * chp;
        }
    }

    // zero BN stat slots
    hipLaunchKernelGGL(zero_kernel, dim3((14 * 128 + 255) / 256), dim3(256), 0, stream, statsBase,
                       14 * 128);

    // prep weights (bf16, transposed, ci-padded)
    for (int l = 0; l < 14; ++l) {
        int chp = CI[l] <= 32 ? 32 : 64;
        int tot = KK[l] * CO[l] * chp;
        hipLaunchKernelGGL(prep_w, dim3((tot + 255) / 256), dim3(256), 0, stream, W[l], WT[l],
                           KK[l], CI[l], CO[l], chp);
    }

    // passthrough outputs
    hipLaunchKernelGGL(copy_kernel, dim3((N0 * 4 + 255) / 256), dim3(256), 0, stream, features, f0,
                       N0 * 4);
    hipLaunchKernelGGL(xyz_kernel, dim3((N0 + 255) / 256), dim3(256), 0, stream, coords0, xyz0, N0,
                       0.05f, 0.05f, 0.1f);
    hipLaunchKernelGGL(xyz_kernel, dim3((N1 + 255) / 256), dim3(256), 0, stream, coords1, xyz1, N1,
                       0.1f, 0.1f, 0.2f);
    hipLaunchKernelGGL(xyz_kernel, dim3((N2 + 255) / 256), dim3(256), 0, stream, coords2, xyz2, N2,
                       0.2f, 0.2f, 0.4f);
    hipLaunchKernelGGL(xyz_kernel, dim3((N3 + 255) / 256), dim3(256), 0, stream, coords3, xyz3, N3,
                       0.4f, 0.4f, 0.8f);

    // f0 -> bf16 padded
    hipLaunchKernelGGL(convert_f0, dim3((N0 * 32 + 255) / 256), dim3(256), 0, stream, features,
                       bfA, N0);

    float* st = statsBase;

    // stage 1
    conv<1, 1, 16>(bfA, rb0, WT[0], preact, st + 0 * 128, N0, 27, stream);
    apply<16, 32, false, true>(preact, st + 0 * 128, G[0], Bb[0], nullptr, bfB, N0, stream);
    conv<1, 1, 16>(bfB, rb0, WT[1], preact, st + 1 * 128, N0, 27, stream);
    apply<16, 32, false, true>(preact, st + 1 * 128, G[1], Bb[1], nullptr, bfA, N0, stream);
    conv<1, 2, 32>(bfA, rbc1, WT[2], preact, st + 2 * 128, N1, 27, stream);
    apply<32, 32, true, true>(preact, st + 2 * 128, G[2], Bb[2], f1, bfB, N1, stream);
    // stage 2
    conv<1, 2, 32>(bfB, rb1, WT[3], preact, st + 3 * 128, N1, 27, stream);
    apply<32, 32, false, true>(preact, st + 3 * 128, G[3], Bb[3], nullptr, bfA, N1, stream);
    conv<1, 2, 32>(bfA, rb1, WT[4], preact, st + 4 * 128, N1, 27, stream);
    apply<32, 32, false, true>(preact, st + 4 * 128, G[4], Bb[4], nullptr, bfB, N1, stream);
    conv<1, 2, 64>(bfB, rbc2, WT[5], preact, st + 5 * 128, N2, 27, stream);
    apply<64, 64, true, true>(preact, st + 5 * 128, G[5], Bb[5], f2, bfA, N2, stream);
    // stage 3
    conv<2, 2, 64>(bfA, rb2, WT[6], preact, st + 6 * 128, N2, 27, stream);
    apply<64, 64, false, true>(preact, st + 6 * 128, G[6], Bb[6], nullptr, bfB, N2, stream);
    conv<2, 2, 64>(bfB, rb2, WT[7], preact, st + 7 * 128, N2, 27, stream);
    apply<64, 64, false, true>(preact, st + 7 * 128, G[7], Bb[7], nullptr, bfA, N2, stream);
    conv<2, 2, 64>(bfA, rb2, WT[8], preact, st + 8 * 128, N2, 27, stream);
    apply<64, 64, false, true>(preact, st + 8 * 128, G[8], Bb[8], nullptr, bfB, N2, stream);
    conv<2, 2, 64>(bfB, rbc3, WT[9], preact, st + 9 * 128, N3, 27, stream);
    apply<64, 64, true, true>(preact, st + 9 * 128, G[9], Bb[9], f3, bfA, N3, stream);
    // stage 4
    conv<2, 2, 64>(bfA, rb3, WT[10], preact, st + 10 * 128, N3, 27, stream);
    apply<64, 64, false, true>(preact, st + 10 * 128, G[10], Bb[10], nullptr, bfB, N3, stream);
    conv<2, 2, 64>(bfB, rb3, WT[11], preact, st + 11 * 128, N3, 27, stream);
    apply<64, 64, false, true>(preact, st + 11 * 128, G[11], Bb[11], nullptr, bfA, N3, stream);
    conv<2, 2, 64>(bfA, rb3, WT[12], preact, st + 12 * 128, N3, 27, stream);
    apply<64, 64, false, true>(preact, st + 12 * 128, G[12], Bb[12], nullptr, bfB, N3, stream);
    conv<2, 2, 64>(bfB, rbc4, WT[13], preact, st + 13 * 128, N4, 3, stream);
    apply<64, 64, true, false>(preact, st + 13 * 128, G[13], Bb[13], f4, nullptr, N4, stream);
}

// Round 4
// 1439.236 us; speedup vs baseline: 3.3928x; 1.6612x over previous
//
#include <hip/hip_runtime.h>

#define BN_EPS 1e-3f

typedef __attribute__((ext_vector_type(8))) short short8;
typedef __attribute__((ext_vector_type(4))) float float4v;

#define NREP 16  // BN stat replicas (atomic contention spread)

__device__ __forceinline__ short f2bf(float f) {
    unsigned u = __float_as_uint(f);
    unsigned r = (u + 0x7FFFu + ((u >> 16) & 1u)) >> 16;
    return (short)r;
}

// ---------------- small utility kernels ----------------

__global__ __launch_bounds__(256) void zero_kernel(float* p, int n) {
    int i = blockIdx.x * 256 + threadIdx.x;
    if (i < n) p[i] = 0.f;
}

__global__ __launch_bounds__(256) void copy_kernel(const float* __restrict__ in,
                                                   float* __restrict__ out, int n) {
    int i = blockIdx.x * 256 + threadIdx.x;
    if (i < n) out[i] = in[i];
}

// coords rows are (b, z, y, x); xyz = (x,y,z) * (voxel*stride) + (0,-40,-3)
__global__ __launch_bounds__(256) void xyz_kernel(const int* __restrict__ coords,
                                                  float* __restrict__ out, int N,
                                                  float sx, float sy, float sz) {
    int n = blockIdx.x * 256 + threadIdx.x;
    if (n >= N) return;
    int4 c = ((const int4*)coords)[n];  // x=b, y=z, z=y, w=x
    out[n * 3 + 0] = c.w * sx;
    out[n * 3 + 1] = c.z * sy - 40.0f;
    out[n * 3 + 2] = c.y * sz - 3.0f;
}

// f0 (N x 4 fp32) -> bf16 padded (N x 32)
__global__ __launch_bounds__(256) void convert_f0(const float* __restrict__ f,
                                                  short* __restrict__ dst, int N) {
    int i = blockIdx.x * 256 + threadIdx.x;
    if (i >= N * 32) return;
    int c = i & 31, n = i >> 5;
    dst[i] = (c < 4) ? f2bf(f[n * 4 + c]) : (short)0;
}

// ---------------- all-layer weight prep: W [K][CIN][COUT] fp32 -> Wt [K][COUT][CHP] bf16 ----
struct PrepAll {
    const float* src[14];
    short* dst[14];
    int K[14];
    int CI[14];
    int CO[14];
    int CHP[14];
    int cum[15];
};

__global__ __launch_bounds__(256) void prep_all_kernel(PrepAll d) {
    int i = blockIdx.x * 256 + threadIdx.x;
    if (i >= d.cum[14]) return;
    int l = 0;
    while (l < 13 && i >= d.cum[l + 1]) ++l;
    int j = i - d.cum[l];
    int chp = d.CHP[l];
    int ci = j % chp;
    int co = (j / chp) % d.CO[l];
    int k = j / (chp * d.CO[l]);
    float v = (ci < d.CI[l]) ? d.src[l][((size_t)k * d.CI[l] + ci) * d.CO[l] + co] : 0.f;
    d.dst[l][j] = f2bf(v);
}

// ---------------- MFMA sparse conv, 1 wave/block, 16 rows x (CT*16) cols ----------------
// feat: bf16 [Nin][CHP]; Wt: bf16 [K][COUT][CHP]; rb: [K][N] (-1 = none)
// Fully unrolled K (template), explicit register double-buffering (no spills),
// all rulebook indices preloaded. BN sum/sumsq fused, atomics into NREP replicas.
template <int CH, int CT, int COUT, int K>
__global__ __launch_bounds__(64) void sconv_mfma(const short* __restrict__ feat,
                                                 const int* __restrict__ rb,
                                                 const short* __restrict__ Wt,
                                                 float* __restrict__ out,
                                                 float* __restrict__ stats, int N) {
    constexpr int CHP = CH * 32;
    const int lane = threadIdx.x;
    const int quad = lane >> 4;
    const int l16 = lane & 15;
    const int m0 = blockIdx.x * 16;
    const int row = m0 + l16;
    const int rowc = (row < N - 1) ? row : (N - 1);
    const int colbase = blockIdx.y * (CT * 16);
    const bool rvalid = (row < N);

    // preload all rulebook indices for this wave's 16 rows
    int idx[K];
#pragma unroll
    for (int k = 0; k < K; ++k) idx[k] = rb[(size_t)k * N + rowc];

    const short* fquad = feat + quad * 8;
    const short* wbase = Wt + (size_t)(colbase + l16) * CHP + quad * 8;

    short8 a[3][CH];      // depth-2 prefetch ring for gathered A rows
    short8 b[2][CH][CT];  // depth-1 double buffer for weights

    auto loadA = [&](short8(&dst)[CH], int k) {
        int ix = idx[k];
        bool v = rvalid && (ix >= 0);
        int cix = ix < 0 ? 0 : ix;
        const short* p = fquad + (size_t)cix * CHP;
#pragma unroll
        for (int c = 0; c < CH; ++c) {
            short8 t = *(const short8*)(p + c * 32);
            dst[c] = v ? t : (short8)0;
        }
    };
    auto loadB = [&](short8(&dst)[CH][CT], int k) {
        const short* p = wbase + (size_t)k * COUT * CHP;
#pragma unroll
        for (int t = 0; t < CT; ++t)
#pragma unroll
            for (int c = 0; c < CH; ++c)
                dst[c][t] = *(const short8*)(p + (size_t)t * 16 * CHP + c * 32);
    };

    float4v acc[CT];
#pragma unroll
    for (int t = 0; t < CT; ++t) acc[t] = (float4v)0.f;

    loadA(a[0], 0);
    if constexpr (K > 1) loadA(a[1], 1);
    loadB(b[0], 0);

#pragma unroll
    for (int k = 0; k < K; ++k) {
        if (k + 2 < K) loadA(a[(k + 2) % 3], k + 2);
        if (k + 1 < K) loadB(b[(k + 1) & 1], k + 1);
#pragma unroll
        for (int c = 0; c < CH; ++c)
#pragma unroll
            for (int t = 0; t < CT; ++t)
                acc[t] = __builtin_amdgcn_mfma_f32_16x16x32_bf16(a[k % 3][c], b[k & 1][c][t],
                                                                 acc[t], 0, 0, 0);
    }

    // D layout: col = lane&15, row = quad*4 + reg
    float* st = stats + (size_t)(blockIdx.x & (NREP - 1)) * 128;
#pragma unroll
    for (int t = 0; t < CT; ++t) {
        int col = colbase + t * 16 + l16;
#pragma unroll
        for (int r = 0; r < 4; ++r) {
            int orow = m0 + quad * 4 + r;
            if (orow < N) out[(size_t)orow * COUT + col] = acc[t][r];
        }
        // fused BN stats (rows >= N contributed exact zeros)
        float s = acc[t][0] + acc[t][1] + acc[t][2] + acc[t][3];
        float ss = acc[t][0] * acc[t][0] + acc[t][1] * acc[t][1] + acc[t][2] * acc[t][2] +
                   acc[t][3] * acc[t][3];
        s += __shfl_xor(s, 16);
        s += __shfl_xor(s, 32);
        ss += __shfl_xor(ss, 16);
        ss += __shfl_xor(ss, 32);
        if (lane < 16) {
            atomicAdd(&st[col], s);
            atomicAdd(&st[64 + col], ss);
        }
    }
}

// ---------------- BN apply + ReLU; replica-reduce in LDS prologue ----------------
// writes bf16 (padded to CHPN) for next layer and/or fp32 output
template <int COUT, int CHPN, bool F32OUT, bool BFOUT>
__global__ __launch_bounds__(256) void bn_apply(const float* __restrict__ x,
                                                const float* __restrict__ stats,
                                                const float* __restrict__ g,
                                                const float* __restrict__ b,
                                                float* __restrict__ fout,
                                                short* __restrict__ bfout, int N) {
    constexpr int CW = BFOUT ? CHPN : COUT;
    __shared__ float ssc[COUT];
    __shared__ float ssh[COUT];
    int tid = threadIdx.x;
    if (tid < COUT) {
        float s = 0.f, q = 0.f;
#pragma unroll
        for (int r = 0; r < NREP; ++r) {
            s += stats[r * 128 + tid];
            q += stats[r * 128 + 64 + tid];
        }
        float inv = 1.0f / (float)N;
        float m = s * inv;
        float v = q * inv - m * m;
        float sc = g[tid] / sqrtf(v + BN_EPS);
        ssc[tid] = sc;
        ssh[tid] = b[tid] - m * sc;
    }
    __syncthreads();
    long i = (long)blockIdx.x * 256 + tid;
    if (i >= (long)N * CW) return;
    int c = (int)(i % CW);
    long n = i / CW;
    float y = 0.f;
    if (c < COUT) {
        y = fmaxf(x[n * COUT + c] * ssc[c] + ssh[c], 0.f);
        if (F32OUT) fout[n * COUT + c] = y;
    }
    if (BFOUT) bfout[n * CHPN + c] = f2bf(y);
}

// ---------------- host helpers ----------------

template <int CH, int CT, int COUT, int K>
static void conv(const short* fin, const int* rb, const short* wt, float* preact, float* stats,
                 int N, hipStream_t stream) {
    dim3 grid((N + 15) / 16, COUT / (CT * 16));
    hipLaunchKernelGGL((sconv_mfma<CH, CT, COUT, K>), grid, dim3(64), 0, stream, fin, rb, wt,
                       preact, stats, N);
}

template <int COUT, int CHPN, bool F32OUT, bool BFOUT>
static void apply(const float* preact, const float* stats, const float* g, const float* b,
                  float* fout, short* bfout, int N, hipStream_t stream) {
    constexpr int CW = BFOUT ? CHPN : COUT;
    int blocks = (int)(((long)N * CW + 255) / 256);
    hipLaunchKernelGGL((bn_apply<COUT, CHPN, F32OUT, BFOUT>), dim3(blocks), dim3(256), 0, stream,
                       preact, stats, g, b, fout, bfout, N);
}

extern "C" void kernel_launch(void* const* d_in, const int* in_sizes, int n_in, void* d_out,
                              int out_size, void* d_ws, size_t ws_size, hipStream_t stream) {
    const float* features = (const float*)d_in[0];
    const float* W[14];
    const float* G[14];
    const float* Bb[14];
    for (int i = 0; i < 14; ++i) {
        W[i] = (const float*)d_in[1 + 3 * i];
        G[i] = (const float*)d_in[2 + 3 * i];
        Bb[i] = (const float*)d_in[3 + 3 * i];
    }
    const int* coords0 = (const int*)d_in[43];
    const int* coords1 = (const int*)d_in[44];
    const int* coords2 = (const int*)d_in[45];
    const int* coords3 = (const int*)d_in[46];
    const int* rb0 = (const int*)d_in[47];
    const int* rbc1 = (const int*)d_in[48];
    const int* rb1 = (const int*)d_in[49];
    const int* rbc2 = (const int*)d_in[50];
    const int* rb2 = (const int*)d_in[51];
    const int* rbc3 = (const int*)d_in[52];
    const int* rb3 = (const int*)d_in[53];
    const int* rbc4 = (const int*)d_in[54];

    const int N0 = in_sizes[0] / 4;
    const int N1 = in_sizes[44] / 4;
    const int N2 = in_sizes[45] / 4;
    const int N3 = in_sizes[46] / 4;
    const int N4 = in_sizes[54] / 3;

    float* out = (float*)d_out;
    long off = 0;
    float* xyz0 = out + off; off += (long)N0 * 3;
    float* f0   = out + off; off += (long)N0 * 4;
    float* xyz1 = out + off; off += (long)N1 * 3;
    float* f1   = out + off; off += (long)N1 * 32;
    float* xyz2 = out + off; off += (long)N2 * 3;
    float* f2   = out + off; off += (long)N2 * 64;
    float* xyz3 = out + off; off += (long)N3 * 3;
    float* f3   = out + off; off += (long)N3 * 64;
    float* f4   = out + off;

    long maxN = N0;
    if (N1 > maxN) maxN = N1;
    if (N2 > maxN) maxN = N2;
    if (N3 > maxN) maxN = N3;
    if (N4 > maxN) maxN = N4;

    // workspace layout
    float* preact = (float*)d_ws;                         // maxN*64 fp32
    float* statsBase = preact + (size_t)maxN * 64;        // 14 * NREP * 128 fp32
    short* bfA = (short*)(statsBase + 14 * NREP * 128);   // maxN*64 bf16
    short* bfB = bfA + (size_t)maxN * 64;                 // maxN*64 bf16
    short* wtBase = bfB + (size_t)maxN * 64;              // transposed bf16 weights

    static const int KK[14] = {27, 27, 27, 27, 27, 27, 27, 27, 27, 27, 27, 27, 27, 3};
    static const int CI[14] = {4, 16, 16, 32, 32, 32, 64, 64, 64, 64, 64, 64, 64, 64};
    static const int CO[14] = {16, 16, 32, 32, 32, 64, 64, 64, 64, 64, 64, 64, 64, 64};
    short* WT[14];
    PrepAll pd;
    {
        size_t o = 0;
        int cum = 0;
        for (int l = 0; l < 14; ++l) {
            WT[l] = wtBase + o;
            int chp = CI[l] <= 32 ? 32 : 64;
            pd.src[l] = W[l];
            pd.dst[l] = WT[l];
            pd.K[l] = KK[l];
            pd.CI[l] = CI[l];
            pd.CO[l] = CO[l];
            pd.CHP[l] = chp;
            pd.cum[l] = cum;
            cum += KK[l] * CO[l] * chp;
            o += (size_t)KK[l] * CO[l] * chp;
        }
        pd.cum[14] = cum;
    }

    // zero BN stat slots
    int nstats = 14 * NREP * 128;
    hipLaunchKernelGGL(zero_kernel, dim3((nstats + 255) / 256), dim3(256), 0, stream, statsBase,
                       nstats);

    // prep all weights in one launch
    hipLaunchKernelGGL(prep_all_kernel, dim3((pd.cum[14] + 255) / 256), dim3(256), 0, stream, pd);

    // passthrough outputs
    hipLaunchKernelGGL(copy_kernel, dim3((N0 * 4 + 255) / 256), dim3(256), 0, stream, features, f0,
                       N0 * 4);
    hipLaunchKernelGGL(xyz_kernel, dim3((N0 + 255) / 256), dim3(256), 0, stream, coords0, xyz0, N0,
                       0.05f, 0.05f, 0.1f);
    hipLaunchKernelGGL(xyz_kernel, dim3((N1 + 255) / 256), dim3(256), 0, stream, coords1, xyz1, N1,
                       0.1f, 0.1f, 0.2f);
    hipLaunchKernelGGL(xyz_kernel, dim3((N2 + 255) / 256), dim3(256), 0, stream, coords2, xyz2, N2,
                       0.2f, 0.2f, 0.4f);
    hipLaunchKernelGGL(xyz_kernel, dim3((N3 + 255) / 256), dim3(256), 0, stream, coords3, xyz3, N3,
                       0.4f, 0.4f, 0.8f);

    // f0 -> bf16 padded
    hipLaunchKernelGGL(convert_f0, dim3((N0 * 32 + 255) / 256), dim3(256), 0, stream, features,
                       bfA, N0);

    float* st = statsBase;
#define STAT(l) (st + (size_t)(l)*NREP * 128)

    // stage 1
    conv<1, 1, 16, 27>(bfA, rb0, WT[0], preact, STAT(0), N0, stream);
    apply<16, 32, false, true>(preact, STAT(0), G[0], Bb[0], nullptr, bfB, N0, stream);
    conv<1, 1, 16, 27>(bfB, rb0, WT[1], preact, STAT(1), N0, stream);
    apply<16, 32, false, true>(preact, STAT(1), G[1], Bb[1], nullptr, bfA, N0, stream);
    conv<1, 2, 32, 27>(bfA, rbc1, WT[2], preact, STAT(2), N1, stream);
    apply<32, 32, true, true>(preact, STAT(2), G[2], Bb[2], f1, bfB, N1, stream);
    // stage 2
    conv<1, 2, 32, 27>(bfB, rb1, WT[3], preact, STAT(3), N1, stream);
    apply<32, 32, false, true>(preact, STAT(3), G[3], Bb[3], nullptr, bfA, N1, stream);
    conv<1, 2, 32, 27>(bfA, rb1, WT[4], preact, STAT(4), N1, stream);
    apply<32, 32, false, true>(preact, STAT(4), G[4], Bb[4], nullptr, bfB, N1, stream);
    conv<1, 2, 64, 27>(bfB, rbc2, WT[5], preact, STAT(5), N2, stream);
    apply<64, 64, true, true>(preact, STAT(5), G[5], Bb[5], f2, bfA, N2, stream);
    // stage 3
    conv<2, 2, 64, 27>(bfA, rb2, WT[6], preact, STAT(6), N2, stream);
    apply<64, 64, false, true>(preact, STAT(6), G[6], Bb[6], nullptr, bfB, N2, stream);
    conv<2, 2, 64, 27>(bfB, rb2, WT[7], preact, STAT(7), N2, stream);
    apply<64, 64, false, true>(preact, STAT(7), G[7], Bb[7], nullptr, bfA, N2, stream);
    conv<2, 2, 64, 27>(bfA, rb2, WT[8], preact, STAT(8), N2, stream);
    apply<64, 64, false, true>(preact, STAT(8), G[8], Bb[8], nullptr, bfB, N2, stream);
    conv<2, 2, 64, 27>(bfB, rbc3, WT[9], preact, STAT(9), N3, stream);
    apply<64, 64, true, true>(preact, STAT(9), G[9], Bb[9], f3, bfA, N3, stream);
    // stage 4
    conv<2, 2, 64, 27>(bfA, rb3, WT[10], preact, STAT(10), N3, stream);
    apply<64, 64, false, true>(preact, STAT(10), G[10], Bb[10], nullptr, bfB, N3, stream);
    conv<2, 2, 64, 27>(bfB, rb3, WT[11], preact, STAT(11), N3, stream);
    apply<64, 64, false, true>(preact, STAT(11), G[11], Bb[11], nullptr, bfA, N3, stream);
    conv<2, 2, 64, 27>(bfA, rb3, WT[12], preact, STAT(12), N3, stream);
    apply<64, 64, false, true>(preact, STAT(12), G[12], Bb[12], nullptr, bfB, N3, stream);
    conv<2, 2, 64, 3>(bfB, rbc4, WT[13], preact, STAT(13), N4, stream);
    apply<64, 64, true, false>(preact, STAT(13), G[13], Bb[13], f4, nullptr, N4, stream);
#undef STAT
}